// Round 1
// baseline (126.523 us; speedup 1.0000x reference)
//
#include <hip/hip_runtime.h>

// Problem constants (fixed by the reference setup)
#define B_   16
#define C_   64
#define H_   128
#define W_   128
#define HO   126
#define WO   126
#define NK   8     // number of conv kernels
#define ROWS 14    // output rows per block (126 = 9 * 14)
#define INR  16    // input rows staged = ROWS + 2

// One block per (band, channel, batch). Stage INR x 128 input rows in LDS with
// SiLU pre-applied, then each thread computes 8 output channels for its
// (row, wo) positions. Writes are coalesced along wo; planes strided by HO*WO.
__global__ __launch_bounds__(256) void conv_silu_kernel(
    const float* __restrict__ x, const float* __restrict__ Wt,
    float* __restrict__ out)
{
    __shared__ float s[INR][W_];   // 16 * 128 * 4 B = 8 KiB

    const int band = blockIdx.x;   // 0..8
    const int c    = blockIdx.y;   // 0..63
    const int b    = blockIdx.z;   // 0..15
    const int tid  = threadIdx.x;  // 0..255
    const int ho0  = band * ROWS;

    // Weights: uniform address + constant indices -> scalar (SGPR) loads.
    float w[NK * 9];
#pragma unroll
    for (int i = 0; i < NK * 9; ++i) w[i] = Wt[i];

    // ---- stage input band (16 rows x 128 cols) with SiLU applied ----
    // 2048 floats = 512 float4; 256 threads x 2 each. Always in-bounds:
    // ho0 max = 112, +15 = 127 = H-1.
    const float4* xv = (const float4*)(x + ((size_t)(b * C_ + c) * H_ + ho0) * W_);
#pragma unroll
    for (int i = 0; i < 2; ++i) {
        const int f   = tid + i * 256;     // float4 index 0..511
        const float4 v = xv[f];
        const int row = f >> 5;            // / 32 float4 per row
        const int col = (f & 31) << 2;
        const float vs[4] = {v.x, v.y, v.z, v.w};
#pragma unroll
        for (int q = 0; q < 4; ++q) {
            const float t = vs[q];
            // silu(t) = t / (1 + exp(-t)) ; fast rcp + hw exp
            s[row][col + q] = t * __builtin_amdgcn_rcpf(1.0f + __expf(-t));
        }
    }
    __syncthreads();

    // ---- compute ----
    const int wo = tid & 127;      // 0..127 (>=126 idle)
    const int ty = tid >> 7;       // 0..1 : row-group
    if (wo >= WO) return;

    float* op = out + ((size_t)(b * (C_ * NK) + c * NK) * HO + ho0) * WO;

#pragma unroll
    for (int it = 0; it < ROWS / 2; ++it) {
        const int r = it * 2 + ty;          // ty=0: rows 0,2,..12 ; ty=1: 1,3,..13
        const float a0 = s[r    ][wo], a1 = s[r    ][wo + 1], a2 = s[r    ][wo + 2];
        const float a3 = s[r + 1][wo], a4 = s[r + 1][wo + 1], a5 = s[r + 1][wo + 2];
        const float a6 = s[r + 2][wo], a7 = s[r + 2][wo + 1], a8 = s[r + 2][wo + 2];
#pragma unroll
        for (int k = 0; k < NK; ++k) {
            const float acc = w[k*9+0]*a0 + w[k*9+1]*a1 + w[k*9+2]*a2
                            + w[k*9+3]*a3 + w[k*9+4]*a4 + w[k*9+5]*a5
                            + w[k*9+6]*a6 + w[k*9+7]*a7 + w[k*9+8]*a8;
            op[((size_t)k * HO + r) * WO + wo] = acc;
        }
    }
}

extern "C" void kernel_launch(void* const* d_in, const int* in_sizes, int n_in,
                              void* d_out, int out_size, void* d_ws, size_t ws_size,
                              hipStream_t stream) {
    const float* x  = (const float*)d_in[0];   // [16,64,128,128] f32
    const float* Wt = (const float*)d_in[1];   // [8,9] f32
    float* out = (float*)d_out;                // [16,512,126,126] f32

    dim3 grid(9, C_, B_);   // (bands, channels, batch)
    conv_silu_kernel<<<grid, 256, 0, stream>>>(x, Wt, out);
}